// Round 7
// baseline (211.496 us; speedup 1.0000x reference)
//
#include <hip/hip_runtime.h>
#include <math.h>

#define D_MODEL 1024
#define T_SEQ   2048
#define NBATCH  4
#define NROWS   (NBATCH * T_SEQ)          // 8192
#define NOUT    64                        // 32 q + 32 k

#define XLD  1032  // xlds row stride (floats): 1024 + 8, 16B aligned

typedef double v4df __attribute__((ext_vector_type(4)));

// ---------- top-4 helpers: total order = (value desc, index asc) ----------
__device__ __forceinline__ bool key_gt(float av, int ai, float bv, int bi) {
    return (av > bv) || (av == bv && ai < bi);
}

__device__ __forceinline__ void cmpswap(float& v0, int& i0, float& v1, int& i1) {
    bool sw = key_gt(v1, i1, v0, i0);
    float nv0 = sw ? v1 : v0, nv1 = sw ? v0 : v1;
    int   ni0 = sw ? i1 : i0, ni1 = sw ? i0 : i1;
    v0 = nv0; v1 = nv1; i0 = ni0; i1 = ni1;
}

// merge sorted-desc a[4] with sorted-desc b[4] -> top4 of union into a (bitonic)
__device__ __forceinline__ void merge4(float (&a)[4], int (&ai)[4],
                                       float b0, int j0, float b1, int j1,
                                       float b2, int j2, float b3, int j3) {
    if (!key_gt(a[0], ai[0], b3, j3)) { a[0] = b3; ai[0] = j3; }
    if (!key_gt(a[1], ai[1], b2, j2)) { a[1] = b2; ai[1] = j2; }
    if (!key_gt(a[2], ai[2], b1, j1)) { a[2] = b1; ai[2] = j1; }
    if (!key_gt(a[3], ai[3], b0, j0)) { a[3] = b0; ai[3] = j0; }
    cmpswap(a[0], ai[0], a[2], ai[2]);
    cmpswap(a[1], ai[1], a[3], ai[3]);
    cmpswap(a[0], ai[0], a[1], ai[1]);
    cmpswap(a[2], ai[2], a[3], ai[3]);
}

// insert candidate (v, idx) into sorted-desc top4; strict > keeps earlier index on ties
__device__ __forceinline__ void insert4(float (&tv)[4], int (&tix)[4], float v, int idx) {
    if (v > tv[3]) {
        bool g0 = v > tv[0], g1 = v > tv[1], g2 = v > tv[2];
        float n0 = g0 ? v : tv[0];
        int   m0 = g0 ? idx : tix[0];
        float n1 = g1 ? (g0 ? tv[0] : v) : tv[1];
        int   m1 = g1 ? (g0 ? tix[0] : idx) : tix[1];
        float n2 = g2 ? (g1 ? tv[1] : v) : tv[2];
        int   m2 = g2 ? (g1 ? tix[1] : idx) : tix[2];
        float n3 = g2 ? tv[2] : v;
        int   m3 = g2 ? tix[2] : idx;
        tv[0] = n0; tv[1] = n1; tv[2] = n2; tv[3] = n3;
        tix[0] = m0; tix[1] = m1; tix[2] = m2; tix[3] = m3;
    }
}

// butterfly merge of per-lane top4 lists across xor-mask m
__device__ __forceinline__ void bfly_merge(float (&tv)[4], int (&tix)[4], int m) {
    float b0 = __shfl_xor(tv[0], m, 64);
    float b1 = __shfl_xor(tv[1], m, 64);
    float b2 = __shfl_xor(tv[2], m, 64);
    float b3 = __shfl_xor(tv[3], m, 64);
    int   j0 = __shfl_xor(tix[0], m, 64);
    int   j1 = __shfl_xor(tix[1], m, 64);
    int   j2 = __shfl_xor(tix[2], m, 64);
    int   j3 = __shfl_xor(tix[3], m, 64);
    merge4(tv, tix, b0, j0, b1, j1, b2, j2, b3, j3);
}

// ---------- Phase 0: probe the f64 MFMA fragment layout in-device ----------
// tab layout (ints): [0]=flag, [1..64]=am, [65..128]=ak, [129..192]=bk,
//                    [193..256]=bn, [257..512]=dm[lane][4], [513..768]=dn[lane][4]
__global__ __launch_bounds__(64) void mfma_probe(int* __restrict__ tab)
{
    __shared__ double Aref[16][4];
    __shared__ double Bref[4][16];
    __shared__ double Dref[16][16];

    const int lane = threadIdx.x;
    {
        const int m = lane & 15, k = lane >> 4;
        Aref[m][k] = (double)(1 + m * 4 + k);     // distinct, asymmetric
        Bref[k][m] = (double)(1 + k * 16 + m);
    }
    __syncthreads();
    for (int e = lane; e < 256; e += 64) {
        const int m = e >> 4, n = e & 15;
        double s = 0.0;
        for (int k = 0; k < 4; ++k) s += Aref[m][k] * Bref[k][n];
        Dref[m][n] = s;   // exact integer-valued f64
    }
    __syncthreads();

    int found = -1;
    for (int h = 0; h < 16; ++h) {
        if (found >= 0) break;
        const int fa = h & 1, fb = (h >> 1) & 1, fd = h >> 2;
        const int am = fa ? (lane >> 2) : (lane & 15);
        const int ak = fa ? (lane & 3)  : (lane >> 4);
        const int bn = fb ? (lane >> 2) : (lane & 15);
        const int bk = fb ? (lane & 3)  : (lane >> 4);
        v4df c = {0.0, 0.0, 0.0, 0.0};
        c = __builtin_amdgcn_mfma_f64_16x16x4f64(Aref[am][ak], Bref[bk][bn], c, 0, 0, 0);
        bool ok = true;
        #pragma unroll
        for (int i = 0; i < 4; ++i) {
            int dm, dn;
            if (fd == 0)      { dm = 4 * (lane >> 4) + i; dn = lane & 15; }
            else if (fd == 1) { dn = 4 * (lane >> 4) + i; dm = lane & 15; }
            else if (fd == 2) { dm = (lane >> 4) + 4 * i; dn = lane & 15; }
            else              { dn = (lane >> 4) + 4 * i; dm = lane & 15; }
            if (c[i] != Dref[dm][dn]) ok = false;
        }
        if (__all(ok)) found = h;
    }

    const int fa = (found >= 0) ? (found & 1) : 0;
    const int fb = (found >= 0) ? ((found >> 1) & 1) : 0;
    const int fd = (found >= 0) ? (found >> 2) : 0;
    tab[1   + lane] = fa ? (lane >> 2) : (lane & 15);
    tab[65  + lane] = fa ? (lane & 3)  : (lane >> 4);
    tab[129 + lane] = fb ? (lane & 3)  : (lane >> 4);
    tab[193 + lane] = fb ? (lane >> 2) : (lane & 15);
    #pragma unroll
    for (int i = 0; i < 4; ++i) {
        int dm, dn;
        if (fd == 0)      { dm = 4 * (lane >> 4) + i; dn = lane & 15; }
        else if (fd == 1) { dn = 4 * (lane >> 4) + i; dm = lane & 15; }
        else if (fd == 2) { dm = (lane >> 4) + 4 * i; dn = lane & 15; }
        else              { dn = (lane >> 4) + 4 * i; dm = lane & 15; }
        tab[257 + lane * 4 + i] = dm;
        tab[513 + lane * 4 + i] = dn;
    }
    if (lane == 0) tab[0] = found;
}

// ---------- Phase 1a: convert W to f64, transposed Wdt[d][64] ----------
__global__ __launch_bounds__(256) void wprep_kernel(
    const float* __restrict__ Wq, const float* __restrict__ Wk,
    double* __restrict__ Wdt)
{
    const int idx = blockIdx.x * 256 + threadIdx.x;   // 65536 total
    const int o = idx & 63;
    const int d = idx >> 6;
    float v = (o < 32) ? Wq[(size_t)o * D_MODEL + d]
                       : Wk[(size_t)(o - 32) * D_MODEL + d];
    Wdt[(size_t)d * 64 + o] = (double)v;
}

// ---------- Phase 1b: projection via f64 MFMA, d-split wave pairs (UNCHANGED R6) ----------
__global__ __launch_bounds__(512) void proj_mfma(
    const float* __restrict__ x, const double* __restrict__ Wdt,
    const float* __restrict__ bq, const float* __restrict__ bk_,
    const int* __restrict__ tab,
    float* __restrict__ Qt, float* __restrict__ Kt)
{
    __shared__ float  xlds[16 * XLD];     // 66048 B
    __shared__ double comb[4][64][4];     // 8192 B

    const int tid  = threadIdx.x;
    const int lane = tid & 63;
    const int wav  = tid >> 6;                                      // 0..7
    const int og   = __builtin_amdgcn_readfirstlane(wav >> 1);      // 0..3
    const int half = __builtin_amdgcn_readfirstlane(wav & 1);       // 0..1
    const int row0 = blockIdx.x * 16;
    const int dbase = half * 512;

    const int flag = tab[0];
    const int am  = tab[1   + lane];
    const int ak  = tab[65  + lane];
    const int bkk = tab[129 + lane];
    const int bn  = tab[193 + lane];

    const double* wcol = Wdt + og * 16;   // + d*64 + bn

    // stage x: 16 rows x 1024 d = 4096 float4, 8 per thread, coalesced
    #pragma unroll
    for (int j = 0; j < 8; ++j) {
        const int f  = j * 512 + tid;
        const int r  = f >> 8;            // 0..15
        const int c4 = f & 255;           // float4 within row
        float4 v = *reinterpret_cast<const float4*>(
            x + (size_t)(row0 + r) * D_MODEL + c4 * 4);
        *reinterpret_cast<float4*>(&xlds[r * XLD + c4 * 4]) = v;
    }
    __syncthreads();

    v4df acc = {0.0, 0.0, 0.0, 0.0};

    if (flag >= 0) {
        #pragma unroll 8
        for (int kk = 0; kk < 128; ++kk) {
            double a = (double)xlds[am * XLD + dbase + kk * 4 + ak];
            double b = wcol[(size_t)(dbase + kk * 4 + bkk) * 64 + bn];
            acc = __builtin_amdgcn_mfma_f64_16x16x4f64(a, b, acc, 0, 0, 0);
        }
    } else {
        const int n  = lane & 15;
        const int r4 = (lane >> 4) * 4;
        for (int dd = 0; dd < 512; ++dd) {
            const int d = dbase + dd;
            double wv = wcol[(size_t)d * 64 + n];
            #pragma unroll
            for (int i = 0; i < 4; ++i)
                acc[i] = fma((double)xlds[(r4 + i) * XLD + d], wv, acc[i]);
        }
    }

    if (half == 1) {
        #pragma unroll
        for (int i = 0; i < 4; ++i) comb[og][lane][i] = acc[i];
    }
    __syncthreads();

    if (half == 0) {
        #pragma unroll
        for (int i = 0; i < 4; ++i) {
            const double tot = acc[i] + comb[og][lane][i];
            const int dmv = tab[257 + lane * 4 + i];
            const int dnv = tab[513 + lane * 4 + i];
            const int out = og * 16 + dnv;
            const int row = row0 + dmv;
            const int bb  = row >> 11, t = row & 2047;
            const double bias = (out < 32) ? (double)bq[out] : (double)bk_[out - 32];
            const float v = (float)(tot + bias);
            if (out < 32) Qt[((size_t)bb * 32 + out) * T_SEQ + t] = v;
            else          Kt[((size_t)bb * 32 + (out - 32)) * T_SEQ + t] = v;
        }
    }
}

// ---------- Phase 2a: sim = Q K^T via f64 MFMA, per-row top-4 over an s-half ----------
// grid 1024 = b(4) x ttile(128, 16 t each) x half(2); block 256 (4 waves).
// Wave w owns s-tiles [w*16, w*16+16) of its half (256 s), processed in ILP-2 pairs.
// A (Q-tile) is loaded once into 8 f64 regs; B (K) read coalesced from L2 per tile.
// acc rounded to f32 -> existing (val desc, idx asc) top-4 machinery.
__global__ __launch_bounds__(256) void sim_mfma(
    const float* __restrict__ Qt, const float* __restrict__ Kt,
    const int* __restrict__ tab,
    float* __restrict__ candVal /* [2][NROWS][4] */,
    int*   __restrict__ candIdx /* [2][NROWS][4] */)
{
    __shared__ float cV[4][16][4];
    __shared__ int   cI[4][16][4];

    const int tid  = threadIdx.x;
    const int lane = tid & 63;
    const int wav  = __builtin_amdgcn_readfirstlane(tid >> 6);   // 0..3
    const int half = blockIdx.x & 1;
    const int tt   = (blockIdx.x >> 1) & 127;
    const int b    = blockIdx.x >> 8;
    const int trow0 = tt * 16;
    const int sbase0 = half * 1024 + wav * 256;

    const float* QtB = Qt + (size_t)b * 32 * T_SEQ;
    const float* KtB = Kt + (size_t)b * 32 * T_SEQ;

    const int flag = tab[0];
    const int am  = tab[1   + lane];
    const int ak  = tab[65  + lane];
    const int bkk = tab[129 + lane];
    const int bn  = tab[193 + lane];
    int dmv[4], dnv[4];
    #pragma unroll
    for (int i = 0; i < 4; ++i) {
        dmv[i] = tab[257 + lane * 4 + i];
        dnv[i] = tab[513 + lane * 4 + i];
    }
    // mode A: dm varies per reg (per-lane 4 row-lists). mode B: dm fixed (1 list).
    const bool modeB = __builtin_amdgcn_readfirstlane((int)(dmv[0] == dmv[1])) != 0;

    // A-fragment: a[c] = Q[t = trow0+am][k = 4c+ak], loaded once
    double a[8];
    #pragma unroll
    for (int c = 0; c < 8; ++c)
        a[c] = (double)QtB[(size_t)(4 * c + ak) * T_SEQ + trow0 + am];

    float tv[4][4]; int tix[4][4];
    #pragma unroll
    for (int r = 0; r < 4; ++r)
        #pragma unroll
        for (int j = 0; j < 4; ++j) { tv[r][j] = -INFINITY; tix[r][j] = 0x7fffffff; }

    for (int pp = 0; pp < 8; ++pp) {
        const int sb0 = sbase0 + pp * 32;
        const int sb1 = sb0 + 16;
        v4df acc0 = {0.0, 0.0, 0.0, 0.0};
        v4df acc1 = {0.0, 0.0, 0.0, 0.0};

        if (flag >= 0) {
            double b0[8], b1[8];
            #pragma unroll
            for (int c = 0; c < 8; ++c) {
                b0[c] = (double)KtB[(size_t)(4 * c + bkk) * T_SEQ + sb0 + bn];
                b1[c] = (double)KtB[(size_t)(4 * c + bkk) * T_SEQ + sb1 + bn];
            }
            #pragma unroll
            for (int c = 0; c < 8; ++c) {
                acc0 = __builtin_amdgcn_mfma_f64_16x16x4f64(a[c], b0[c], acc0, 0, 0, 0);
                acc1 = __builtin_amdgcn_mfma_f64_16x16x4f64(a[c], b1[c], acc1, 0, 0, 0);
            }
        } else {
            // scalar fallback: compute exactly the elements this lane holds
            #pragma unroll
            for (int i = 0; i < 4; ++i) {
                double s0 = 0.0, s1 = 0.0;
                for (int k = 0; k < 32; ++k) {
                    double q = (double)QtB[(size_t)k * T_SEQ + trow0 + dmv[i]];
                    s0 = fma(q, (double)KtB[(size_t)k * T_SEQ + sb0 + dnv[i]], s0);
                    s1 = fma(q, (double)KtB[(size_t)k * T_SEQ + sb1 + dnv[i]], s1);
                }
                acc0[i] = s0; acc1[i] = s1;
            }
        }

        if (!modeB) {
            // rows dm[i], col dn (constant across i)
            #pragma unroll
            for (int i = 0; i < 4; ++i) {
                insert4(tv[i], tix[i], (float)acc0[i], sb0 + dnv[i]);
                insert4(tv[i], tix[i], (float)acc1[i], sb1 + dnv[i]);
            }
        } else {
            // one row (dm const), 4 cols dn[i]
            #pragma unroll
            for (int i = 0; i < 4; ++i) {
                insert4(tv[0], tix[0], (float)acc0[i], sb0 + dnv[i]);
                insert4(tv[0], tix[0], (float)acc1[i], sb1 + dnv[i]);
            }
        }
    }

    // intra-wave merge + write 16 row-lists to LDS
    if (!modeB) {
        // lanes in a quad share {dm[i]}; butterfly over low 4 bits (dn lanes)
        bfly_merge(tv[0], tix[0], 1); bfly_merge(tv[0], tix[0], 2);
        bfly_merge(tv[0], tix[0], 4); bfly_merge(tv[0], tix[0], 8);
        bfly_merge(tv[1], tix[1], 1); bfly_merge(tv[1], tix[1], 2);
        bfly_merge(tv[1], tix[1], 4); bfly_merge(tv[1], tix[1], 8);
        bfly_merge(tv[2], tix[2], 1); bfly_merge(tv[2], tix[2], 2);
        bfly_merge(tv[2], tix[2], 4); bfly_merge(tv[2], tix[2], 8);
        bfly_merge(tv[3], tix[3], 1); bfly_merge(tv[3], tix[3], 2);
        bfly_merge(tv[3], tix[3], 4); bfly_merge(tv[3], tix[3], 8);
        if ((lane & 15) == 0) {
            #pragma unroll
            for (int i = 0; i < 4; ++i)
                #pragma unroll
                for (int j = 0; j < 4; ++j) {
                    cV[wav][dmv[i]][j] = tv[i][j];
                    cI[wav][dmv[i]][j] = tix[i][j];
                }
        }
    } else {
        // lanes sharing dm = lane&15 sit at xor 16/32
        bfly_merge(tv[0], tix[0], 16);
        bfly_merge(tv[0], tix[0], 32);
        if (lane < 16) {
            #pragma unroll
            for (int j = 0; j < 4; ++j) {
                cV[wav][lane][j] = tv[0][j];
                cI[wav][lane][j] = tix[0][j];
            }
        }
    }
    __syncthreads();

    // cross-wave merge (4 waves), write per-half candidate lists
    if (tid < 16) {
        float mv[4]; int mi[4];
        #pragma unroll
        for (int j = 0; j < 4; ++j) { mv[j] = cV[0][tid][j]; mi[j] = cI[0][tid][j]; }
        #pragma unroll
        for (int w = 1; w < 4; ++w)
            merge4(mv, mi,
                   cV[w][tid][0], cI[w][tid][0],
                   cV[w][tid][1], cI[w][tid][1],
                   cV[w][tid][2], cI[w][tid][2],
                   cV[w][tid][3], cI[w][tid][3]);
        const size_t row = (size_t)b * T_SEQ + trow0 + tid;
        float4 vv = {mv[0], mv[1], mv[2], mv[3]};
        int4   ii = {mi[0], mi[1], mi[2], mi[3]};
        *reinterpret_cast<float4*>(candVal + ((size_t)half * NROWS + row) * 4) = vv;
        *reinterpret_cast<int4*>(candIdx + ((size_t)half * NROWS + row) * 4) = ii;
    }
}

// ---------- Phase 2b: merge halves + fused gather/mean ----------
// grid 1024 (8 rows/block), block 256 thr
__global__ __launch_bounds__(256) void merge_gather(
    const float* __restrict__ x,
    const float* __restrict__ candVal, const int* __restrict__ candIdx,
    float* __restrict__ out)
{
    __shared__ int topIdx[8][4];

    const int tid  = threadIdx.x;
    const int row0 = blockIdx.x * 8;
    const int b    = row0 >> 11;

    if (tid < 8) {
        const size_t row = row0 + tid;
        float4 v0 = *reinterpret_cast<const float4*>(candVal + row * 4);
        int4   i0 = *reinterpret_cast<const int4*>(candIdx + row * 4);
        float4 v1 = *reinterpret_cast<const float4*>(candVal + ((size_t)NROWS + row) * 4);
        int4   i1 = *reinterpret_cast<const int4*>(candIdx + ((size_t)NROWS + row) * 4);
        float mv[4] = {v0.x, v0.y, v0.z, v0.w};
        int   mi[4] = {i0.x, i0.y, i0.z, i0.w};
        merge4(mv, mi, v1.x, i1.x, v1.y, i1.y, v1.z, i1.z, v1.w, i1.w);
        #pragma unroll
        for (int j = 0; j < 4; ++j) topIdx[tid][j] = mi[j];
    }
    __syncthreads();

    const float* xb = x + (size_t)b * T_SEQ * D_MODEL;
    float* ob = out + (size_t)row0 * D_MODEL;
    #pragma unroll
    for (int r = 0; r < 8; ++r) {
        const int i0 = topIdx[r][0], i1 = topIdx[r][1], i2 = topIdx[r][2], i3 = topIdx[r][3];
        float4 a0 = *(reinterpret_cast<const float4*>(xb + (size_t)i0 * D_MODEL) + tid);
        float4 a1 = *(reinterpret_cast<const float4*>(xb + (size_t)i1 * D_MODEL) + tid);
        float4 a2 = *(reinterpret_cast<const float4*>(xb + (size_t)i2 * D_MODEL) + tid);
        float4 a3 = *(reinterpret_cast<const float4*>(xb + (size_t)i3 * D_MODEL) + tid);
        float4 o;
        o.x = (a0.x + a1.x + a2.x + a3.x) * 0.25f;
        o.y = (a0.y + a1.y + a2.y + a3.y) * 0.25f;
        o.z = (a0.z + a1.z + a2.z + a3.z) * 0.25f;
        o.w = (a0.w + a1.w + a2.w + a3.w) * 0.25f;
        *(reinterpret_cast<float4*>(ob + (size_t)r * D_MODEL) + tid) = o;
    }
}

extern "C" void kernel_launch(void* const* d_in, const int* in_sizes, int n_in,
                              void* d_out, int out_size, void* d_ws, size_t ws_size,
                              hipStream_t stream) {
    const float* x  = (const float*)d_in[0];
    const float* Wq = (const float*)d_in[1];
    const float* bq = (const float*)d_in[2];
    const float* Wk = (const float*)d_in[3];
    const float* bk = (const float*)d_in[4];
    float* out = (float*)d_out;

    // ws layout: [tab 4KB][Wdt 512KB][Qt 1MB][Kt 1MB][candVal 256KB][candIdx 256KB]
    char* wsb = (char*)d_ws;
    int*    tab  = (int*)wsb;                                            // 4 KB reserved
    double* Wdt  = (double*)(wsb + 4096);                                // 512 KB
    float*  Qt   = (float*)(wsb + 4096 + (size_t)D_MODEL * NOUT * 8);    // 1 MB
    float*  Kt   = Qt + (size_t)NBATCH * 32 * T_SEQ;                     // 1 MB
    float*  candVal = (float*)((char*)Kt + (size_t)NBATCH * 32 * T_SEQ * 4);
    int*    candIdx = (int*)((char*)candVal + (size_t)2 * NROWS * 4 * 4);

    mfma_probe<<<dim3(1), dim3(64), 0, stream>>>(tab);
    wprep_kernel<<<dim3(256), dim3(256), 0, stream>>>(Wq, Wk, Wdt);
    proj_mfma<<<dim3(NROWS / 16), dim3(512), 0, stream>>>(x, Wdt, bq, bk, tab, Qt, Kt);
    sim_mfma<<<dim3(1024), dim3(256), 0, stream>>>(Qt, Kt, tab, candVal, candIdx);
    merge_gather<<<dim3(1024), dim3(256), 0, stream>>>(x, candVal, candIdx, out);
}

// Round 8
// 175.015 us; speedup vs baseline: 1.2084x; 1.2084x over previous
//
#include <hip/hip_runtime.h>
#include <math.h>

#define D_MODEL 1024
#define T_SEQ   2048
#define NBATCH  4
#define NROWS   (NBATCH * T_SEQ)          // 8192
#define NOUT    64                        // 32 q + 32 k
#define NQTR    4                         // s-quarters in sim

#define SKLD 264   // klds row stride (floats): 256 + 8, 16B aligned, <=2-way banks
#define SQLD 36    // qlds row stride (floats): 32 + 4

typedef double v4df __attribute__((ext_vector_type(4)));

// ---------- top-4 helpers: total order = (value desc, index asc) ----------
__device__ __forceinline__ bool key_gt(float av, int ai, float bv, int bi) {
    return (av > bv) || (av == bv && ai < bi);
}

__device__ __forceinline__ void cmpswap(float& v0, int& i0, float& v1, int& i1) {
    bool sw = key_gt(v1, i1, v0, i0);
    float nv0 = sw ? v1 : v0, nv1 = sw ? v0 : v1;
    int   ni0 = sw ? i1 : i0, ni1 = sw ? i0 : i1;
    v0 = nv0; v1 = nv1; i0 = ni0; i1 = ni1;
}

// merge sorted-desc a[4] with sorted-desc b[4] -> top4 of union into a (bitonic)
__device__ __forceinline__ void merge4(float (&a)[4], int (&ai)[4],
                                       float b0, int j0, float b1, int j1,
                                       float b2, int j2, float b3, int j3) {
    if (!key_gt(a[0], ai[0], b3, j3)) { a[0] = b3; ai[0] = j3; }
    if (!key_gt(a[1], ai[1], b2, j2)) { a[1] = b2; ai[1] = j2; }
    if (!key_gt(a[2], ai[2], b1, j1)) { a[2] = b1; ai[2] = j1; }
    if (!key_gt(a[3], ai[3], b0, j0)) { a[3] = b0; ai[3] = j0; }
    cmpswap(a[0], ai[0], a[2], ai[2]);
    cmpswap(a[1], ai[1], a[3], ai[3]);
    cmpswap(a[0], ai[0], a[1], ai[1]);
    cmpswap(a[2], ai[2], a[3], ai[3]);
}

// insert candidate (v, idx) into sorted-desc top4; strict > keeps earlier index on ties
__device__ __forceinline__ void insert4(float (&tv)[4], int (&tix)[4], float v, int idx) {
    if (v > tv[3]) {
        bool g0 = v > tv[0], g1 = v > tv[1], g2 = v > tv[2];
        float n0 = g0 ? v : tv[0];
        int   m0 = g0 ? idx : tix[0];
        float n1 = g1 ? (g0 ? tv[0] : v) : tv[1];
        int   m1 = g1 ? (g0 ? tix[0] : idx) : tix[1];
        float n2 = g2 ? (g1 ? tv[1] : v) : tv[2];
        int   m2 = g2 ? (g1 ? tix[1] : idx) : tix[2];
        float n3 = g2 ? tv[2] : v;
        int   m3 = g2 ? tix[2] : idx;
        tv[0] = n0; tv[1] = n1; tv[2] = n2; tv[3] = n3;
        tix[0] = m0; tix[1] = m1; tix[2] = m2; tix[3] = m3;
    }
}

// ---------- self-probe: f64 MFMA fragment layout, pure registers (no LDS/sync) ----------
// A/B references are closed-form: A[m][k] = 1+4m+k, B[k][n] = 1+16k+n (exact in f64).
// Tests 16 (fA,fB,fD) hypotheses; outputs per-lane fragment maps (placeholder identity
// maps + flag=-1 if none match -> scalar fallback paths).
__device__ __forceinline__ void probe_f64(int lane, int& flag,
                                          int& am, int& ak, int& bkk, int& bn,
                                          int (&dmv)[4], int (&dnv)[4]) {
    int found = -1;
    for (int h = 0; h < 16; ++h) {
        if (found >= 0) break;                       // wave-uniform
        const int fa = h & 1, fb = (h >> 1) & 1, fd = h >> 2;
        const int tam = fa ? (lane >> 2) : (lane & 15);
        const int tak = fa ? (lane & 3)  : (lane >> 4);
        const int tbn = fb ? (lane >> 2) : (lane & 15);
        const int tbk = fb ? (lane & 3)  : (lane >> 4);
        const double a = (double)(1 + tam * 4 + tak);
        const double b = (double)(1 + tbk * 16 + tbn);
        v4df c = {0.0, 0.0, 0.0, 0.0};
        c = __builtin_amdgcn_mfma_f64_16x16x4f64(a, b, c, 0, 0, 0);
        bool ok = true;
        #pragma unroll
        for (int i = 0; i < 4; ++i) {
            int dm, dn;
            if (fd == 0)      { dm = 4 * (lane >> 4) + i; dn = lane & 15; }
            else if (fd == 1) { dn = 4 * (lane >> 4) + i; dm = lane & 15; }
            else if (fd == 2) { dm = (lane >> 4) + 4 * i; dn = lane & 15; }
            else              { dn = (lane >> 4) + 4 * i; dm = lane & 15; }
            double ref = 0.0;
            #pragma unroll
            for (int k = 0; k < 4; ++k)
                ref += (double)((1 + 4 * dm + k) * (1 + 16 * k + dn));
            if (c[i] != ref) ok = false;             // exact integer compare
        }
        if (__all(ok)) found = h;
    }
    flag = found;
    const int fa = (found >= 0) ? (found & 1) : 0;
    const int fb = (found >= 0) ? ((found >> 1) & 1) : 0;
    const int fd = (found >= 0) ? (found >> 2) : 0;
    am  = fa ? (lane >> 2) : (lane & 15);
    ak  = fa ? (lane & 3)  : (lane >> 4);
    bn  = fb ? (lane >> 2) : (lane & 15);
    bkk = fb ? (lane & 3)  : (lane >> 4);
    #pragma unroll
    for (int i = 0; i < 4; ++i) {
        if (fd == 0)      { dmv[i] = 4 * (lane >> 4) + i; dnv[i] = lane & 15; }
        else if (fd == 1) { dnv[i] = 4 * (lane >> 4) + i; dmv[i] = lane & 15; }
        else if (fd == 2) { dmv[i] = (lane >> 4) + 4 * i; dnv[i] = lane & 15; }
        else              { dnv[i] = (lane >> 4) + 4 * i; dmv[i] = lane & 15; }
    }
}

// ---------- Phase 1a: W -> f64 fragment order: Wfrag[og][kk][lane] ----------
// Wfrag[og][kk][l] = W[og*16 + bn(l)][4*kk + bkk(l)], W = [Wq;Wk] rows.
// grid 256 x 256 thr; writes fully coalesced (lane-consecutive).
__global__ __launch_bounds__(256) void wprep_kernel(
    const float* __restrict__ Wq, const float* __restrict__ Wk,
    double* __restrict__ Wfrag)
{
    const int lane = threadIdx.x & 63;
    int flag, am, ak, bkk, bn, dmv[4], dnv[4];
    probe_f64(lane, flag, am, ak, bkk, bn, dmv, dnv);

    const int g  = blockIdx.x * 256 + threadIdx.x;   // 65536 = 4 og x 256 kk x 64 l
    const int kk = (g >> 6) & 255;
    const int og = g >> 14;
    const int o  = og * 16 + bn;
    const int d  = kk * 4 + bkk;
    const float v = (o < 32) ? Wq[(size_t)o * D_MODEL + d]
                             : Wk[(size_t)(o - 32) * D_MODEL + d];
    Wfrag[((size_t)og * 256 + kk) * 64 + lane] = (double)v;
}

// ---------- Phase 1b: projection via f64 MFMA, fragment-order feeds ----------
// grid 512 (16 rows each), block 512 (8 waves): wave = (og = wav>>1, half = wav&1).
// A: aFrag[kk][lane] in LDS (destination-major staging, conflict-free reads).
// B: Wfrag global, lane-consecutive dwordx2, L2-resident.
// Operand values & MFMA order bitwise-identical to prior passing round.
__global__ __launch_bounds__(512) void proj_mfma(
    const float* __restrict__ x, const double* __restrict__ Wfrag,
    const float* __restrict__ bq, const float* __restrict__ bk_,
    float* __restrict__ Qt, float* __restrict__ Kt)
{
    __shared__ float  aFrag[256 * 64];    // 65536 B: aFrag[kk][l] = x[row0+am(l)][4kk+ak(l)]
    __shared__ double comb[4][64][4];     // 8192 B

    const int tid  = threadIdx.x;
    const int lane = tid & 63;
    const int wav  = tid >> 6;                                      // 0..7
    const int og   = __builtin_amdgcn_readfirstlane(wav >> 1);      // 0..3
    const int half = __builtin_amdgcn_readfirstlane(wav & 1);       // 0..1
    const int row0 = blockIdx.x * 16;

    int flag, am, ak, bkk, bn, dmv[4], dnv[4];
    probe_f64(lane, flag, am, ak, bkk, bn, dmv, dnv);
    (void)bkk; (void)bn;   // baked into Wfrag by wprep

    // destination-major staging: wave w fills kk in [w*32, w*32+32)
    {
        const float* xr = x + (size_t)(row0 + am) * D_MODEL + ak;
        #pragma unroll 8
        for (int kq = 0; kq < 32; ++kq) {
            const int kk = wav * 32 + kq;
            aFrag[kk * 64 + lane] = xr[kk * 4];
        }
    }
    __syncthreads();

    v4df acc = {0.0, 0.0, 0.0, 0.0};

    if (flag >= 0) {
        const double* wf = Wfrag + ((size_t)og * 256 + half * 128) * 64 + lane;
        const float*  af = aFrag + half * 128 * 64 + lane;
        #pragma unroll 8
        for (int kk = 0; kk < 128; ++kk) {
            double a = (double)af[kk * 64];
            double b = wf[(size_t)kk * 64];
            acc = __builtin_amdgcn_mfma_f64_16x16x4f64(a, b, acc, 0, 0, 0);
        }
    } else {
        // scalar fallback under placeholder maps: out n = lane&15, rows r4..r4+3
        const int n  = lane & 15;
        const int r4 = (lane >> 4) * 4;
        for (int dd = 0; dd < 512; ++dd) {
            const int d = half * 512 + dd;
            const double wv = Wfrag[((size_t)og * 256 + (d >> 2)) * 64 + (((d & 3) << 4) | n)];
            #pragma unroll
            for (int i = 0; i < 4; ++i)
                acc[i] = fma((double)aFrag[(d >> 2) * 64 + (((d & 3) << 4) | (r4 + i))], wv, acc[i]);
        }
    }

    if (half == 1) {
        #pragma unroll
        for (int i = 0; i < 4; ++i) comb[og][lane][i] = acc[i];
    }
    __syncthreads();

    if (half == 0) {
        // total = low + high (fixed order -> deterministic), + bias, store
        #pragma unroll
        for (int i = 0; i < 4; ++i) {
            const double tot = acc[i] + comb[og][lane][i];
            const int out = og * 16 + dnv[i];
            const int row = row0 + dmv[i];
            const int bb  = row >> 11, t = row & 2047;
            const double bias = (out < 32) ? (double)bq[out] : (double)bk_[out - 32];
            const float v = (float)(tot + bias);
            if (out < 32) Qt[((size_t)bb * 32 + out) * T_SEQ + t] = v;
            else          Kt[((size_t)bb * 32 + (out - 32)) * T_SEQ + t] = v;
        }
    }
}

// ---------- Phase 2a: sim over an s-quarter, per-row top-4 -> ws (R6 verbatim) ----------
// grid 1024 = b(4) x ttile(64) x quarter(4); block 256 (4 waves)
__global__ __launch_bounds__(256) void sim_topk(
    const float* __restrict__ Qt, const float* __restrict__ Kt,
    float* __restrict__ candVal /* [NQTR][NROWS][4] */,
    int*   __restrict__ candIdx /* [NQTR][NROWS][4] */)
{
    __shared__ float klds[32 * SKLD];     // 33792 B
    __shared__ float qlds[32 * SQLD];     // 4608 B
    __shared__ float cV[4][32][4];
    __shared__ int   cI[4][32][4];

    const int tid  = threadIdx.x;
    const int lane = tid & 63;
    const int wav  = tid >> 6;            // 0..3
    const int qtr  = blockIdx.x & 3;
    const int tt   = (blockIdx.x >> 2) & 63;
    const int b    = blockIdx.x >> 8;
    const int tblk = tt * 32;
    const int sq0  = qtr * 512;

    const float* QtB = Qt + (size_t)b * 32 * T_SEQ;
    const float* KtB = Kt + (size_t)b * 32 * T_SEQ;

    // stage Q^T tile: 32 i x 32 t (exactly 256 float4s)
    {
        const int i  = tid >> 3;
        const int t4 = (tid & 7) * 4;
        float4 v = *reinterpret_cast<const float4*>(QtB + (size_t)i * T_SEQ + tblk + t4);
        *reinterpret_cast<float4*>(&qlds[i * SQLD + t4]) = v;
    }

    const int t0 = (tid & 7) * 4;         // 8 t-groups x 4 rows
    const int s0 = (tid >> 3) * 8;        // 32 s-groups x 8

    float tv[4][4]; int tix[4][4];
    #pragma unroll
    for (int r = 0; r < 4; ++r)
        #pragma unroll
        for (int j = 0; j < 4; ++j) { tv[r][j] = -INFINITY; tix[r][j] = 0x7fffffff; }

    for (int st = 0; st < 2; ++st) {
        __syncthreads();
        #pragma unroll
        for (int j = 0; j < 8; ++j) {
            const int f  = (tid + j * 256) * 4;
            const int ki = f >> 8;
            const int ks = f & 255;
            float4 v = *reinterpret_cast<const float4*>(
                KtB + (size_t)ki * T_SEQ + sq0 + st * 256 + ks);
            *reinterpret_cast<float4*>(&klds[ki * SKLD + ks]) = v;
        }
        __syncthreads();

        float acc[4][8];
        #pragma unroll
        for (int r = 0; r < 4; ++r)
            #pragma unroll
            for (int c = 0; c < 8; ++c) acc[r][c] = 0.f;

        #pragma unroll 4
        for (int i = 0; i < 32; ++i) {
            float4 qv  = *reinterpret_cast<const float4*>(&qlds[i * SQLD + t0]);
            float4 kv0 = *reinterpret_cast<const float4*>(&klds[i * SKLD + s0]);
            float4 kv1 = *reinterpret_cast<const float4*>(&klds[i * SKLD + s0 + 4]);
            const float qa[4] = {qv.x, qv.y, qv.z, qv.w};
            const float ka[8] = {kv0.x, kv0.y, kv0.z, kv0.w, kv1.x, kv1.y, kv1.z, kv1.w};
            #pragma unroll
            for (int r = 0; r < 4; ++r)
                #pragma unroll
                for (int c = 0; c < 8; ++c)
                    acc[r][c] = fmaf(qa[r], ka[c], acc[r][c]);
        }

        const int sbase = sq0 + st * 256 + s0;
        #pragma unroll
        for (int c = 0; c < 8; ++c)
            #pragma unroll
            for (int r = 0; r < 4; ++r)
                insert4(tv[r], tix[r], acc[r][c], sbase + c);
    }

    // wave butterfly: masks 8..32 preserve t-group (lane&7)
    #pragma unroll
    for (int m = 8; m <= 32; m <<= 1) {
        #pragma unroll
        for (int r = 0; r < 4; ++r) {
            float b0 = __shfl_xor(tv[r][0], m, 64);
            float b1 = __shfl_xor(tv[r][1], m, 64);
            float b2 = __shfl_xor(tv[r][2], m, 64);
            float b3 = __shfl_xor(tv[r][3], m, 64);
            int   j0 = __shfl_xor(tix[r][0], m, 64);
            int   j1 = __shfl_xor(tix[r][1], m, 64);
            int   j2 = __shfl_xor(tix[r][2], m, 64);
            int   j3 = __shfl_xor(tix[r][3], m, 64);
            merge4(tv[r], tix[r], b0, j0, b1, j1, b2, j2, b3, j3);
        }
    }

    if (lane < 8) {
        #pragma unroll
        for (int r = 0; r < 4; ++r)
            #pragma unroll
            for (int j = 0; j < 4; ++j) {
                cV[wav][lane * 4 + r][j] = tv[r][j];
                cI[wav][lane * 4 + r][j] = tix[r][j];
            }
    }
    __syncthreads();

    // cross-wave merge (4 waves), write per-quarter candidate lists
    if (tid < 32) {
        float mv[4]; int mi[4];
        #pragma unroll
        for (int j = 0; j < 4; ++j) { mv[j] = cV[0][tid][j]; mi[j] = cI[0][tid][j]; }
        #pragma unroll
        for (int w = 1; w < 4; ++w)
            merge4(mv, mi,
                   cV[w][tid][0], cI[w][tid][0],
                   cV[w][tid][1], cI[w][tid][1],
                   cV[w][tid][2], cI[w][tid][2],
                   cV[w][tid][3], cI[w][tid][3]);
        const size_t row = (size_t)b * T_SEQ + tblk + tid;
        float4 vv = {mv[0], mv[1], mv[2], mv[3]};
        int4   ii = {mi[0], mi[1], mi[2], mi[3]};
        *reinterpret_cast<float4*>(candVal + ((size_t)qtr * NROWS + row) * 4) = vv;
        *reinterpret_cast<int4*>(candIdx + ((size_t)qtr * NROWS + row) * 4) = ii;
    }
}

// ---------- Phase 2b: merge quarters + fused gather/mean (R6 verbatim) ----------
__global__ __launch_bounds__(256) void merge_gather(
    const float* __restrict__ x,
    const float* __restrict__ candVal, const int* __restrict__ candIdx,
    float* __restrict__ out)
{
    __shared__ int topIdx[8][4];

    const int tid  = threadIdx.x;
    const int row0 = blockIdx.x * 8;
    const int b    = row0 >> 11;

    if (tid < 8) {
        const size_t row = row0 + tid;
        float4 v0 = *reinterpret_cast<const float4*>(candVal + row * 4);
        int4   i0 = *reinterpret_cast<const int4*>(candIdx + row * 4);
        float mv[4] = {v0.x, v0.y, v0.z, v0.w};
        int   mi[4] = {i0.x, i0.y, i0.z, i0.w};
        #pragma unroll
        for (int q = 1; q < NQTR; ++q) {
            float4 v1 = *reinterpret_cast<const float4*>(candVal + ((size_t)q * NROWS + row) * 4);
            int4   i1 = *reinterpret_cast<const int4*>(candIdx + ((size_t)q * NROWS + row) * 4);
            merge4(mv, mi, v1.x, i1.x, v1.y, i1.y, v1.z, i1.z, v1.w, i1.w);
        }
        #pragma unroll
        for (int j = 0; j < 4; ++j) topIdx[tid][j] = mi[j];
    }
    __syncthreads();

    const float* xb = x + (size_t)b * T_SEQ * D_MODEL;
    float* ob = out + (size_t)row0 * D_MODEL;
    #pragma unroll
    for (int r = 0; r < 8; ++r) {
        const int i0 = topIdx[r][0], i1 = topIdx[r][1], i2 = topIdx[r][2], i3 = topIdx[r][3];
        float4 a0 = *(reinterpret_cast<const float4*>(xb + (size_t)i0 * D_MODEL) + tid);
        float4 a1 = *(reinterpret_cast<const float4*>(xb + (size_t)i1 * D_MODEL) + tid);
        float4 a2 = *(reinterpret_cast<const float4*>(xb + (size_t)i2 * D_MODEL) + tid);
        float4 a3 = *(reinterpret_cast<const float4*>(xb + (size_t)i3 * D_MODEL) + tid);
        float4 o;
        o.x = (a0.x + a1.x + a2.x + a3.x) * 0.25f;
        o.y = (a0.y + a1.y + a2.y + a3.y) * 0.25f;
        o.z = (a0.z + a1.z + a2.z + a3.z) * 0.25f;
        o.w = (a0.w + a1.w + a2.w + a3.w) * 0.25f;
        *(reinterpret_cast<float4*>(ob + (size_t)r * D_MODEL) + tid) = o;
    }
}

extern "C" void kernel_launch(void* const* d_in, const int* in_sizes, int n_in,
                              void* d_out, int out_size, void* d_ws, size_t ws_size,
                              hipStream_t stream) {
    const float* x  = (const float*)d_in[0];
    const float* Wq = (const float*)d_in[1];
    const float* bq = (const float*)d_in[2];
    const float* Wk = (const float*)d_in[3];
    const float* bk = (const float*)d_in[4];
    float* out = (float*)d_out;

    // ws layout: [Wfrag 512KB][Qt 1MB][Kt 1MB][candVal 512KB][candIdx 512KB]
    char* wsb = (char*)d_ws;
    double* Wfrag = (double*)wsb;                                        // 4*256*64*8 = 512 KB
    float*  Qt    = (float*)(wsb + (size_t)4 * 256 * 64 * 8);            // 1 MB
    float*  Kt    = Qt + (size_t)NBATCH * 32 * T_SEQ;                    // 1 MB
    float*  candVal = (float*)((char*)Kt + (size_t)NBATCH * 32 * T_SEQ * 4);
    int*    candIdx = (int*)((char*)candVal + (size_t)NQTR * NROWS * 4 * 4);

    wprep_kernel<<<dim3(256), dim3(256), 0, stream>>>(Wq, Wk, Wfrag);
    proj_mfma<<<dim3(NROWS / 16), dim3(512), 0, stream>>>(x, Wfrag, bq, bk, Qt, Kt);
    sim_topk<<<dim3(1024), dim3(256), 0, stream>>>(Qt, Kt, candVal, candIdx);
    merge_gather<<<dim3(1024), dim3(256), 0, stream>>>(x, candVal, candIdx, out);
}